// Round 14
// baseline (633.023 us; speedup 1.0000x reference)
//
#include <hip/hip_runtime.h>

#define TT 100
#define DD 100
#define DC 25      // DD/4
#define PP 10
#define BBATCH 256
#define OC 80
#define NW 8       // waves per block (512 threads)
#define NR 2       // rows per wave per group

typedef float v2f __attribute__((ext_vector_type(2)));
typedef float v4f __attribute__((ext_vector_type(4)));
typedef _Float16 f16x8 __attribute__((ext_vector_type(8)));

static constexpr float FEPS = 1e-6f;
static constexpr float WSCALE   = 16777216.f;              // 2^24: keeps s1*w^2 out of f16 subnormal range
static constexpr float WSCALE_I = 5.9604644775390625e-8f;  // 2^-24

__device__ __forceinline__ int   f2i(float x) { return __builtin_bit_cast(int, x); }
__device__ __forceinline__ float i2f(int x)   { return __builtin_bit_cast(float, x); }

// DPP row_ror:n within 16-lane rows — VALU pipe, no LDS traffic.
#define ROR_F(v, ctrl) i2f(__builtin_amdgcn_update_dpp(0, f2i(v), (ctrl), 0xf, 0xf, false))
#define ROR_I(v, ctrl) __builtin_amdgcn_update_dpp(0, (v), (ctrl), 0xf, 0xf, false)

__device__ __forceinline__ v2f xswap32_f(float v) {
#if __has_builtin(__builtin_amdgcn_permlane32_swap)
  auto pr = __builtin_amdgcn_permlane32_swap((unsigned)f2i(v), (unsigned)f2i(v), false, false);
  v2f r; r.x = i2f((int)pr[0]); r.y = i2f((int)pr[1]);
  return r;
#else
  v2f r; r.x = v; r.y = __shfl_xor(v, 32, 64);
  return r;
#endif
}

__device__ __forceinline__ float wave_sum(float v) {
  v += ROR_F(v, 0x121);
  v += ROR_F(v, 0x122);
  v += ROR_F(v, 0x124);
  v += ROR_F(v, 0x128);
  v += i2f(__builtin_amdgcn_ds_swizzle(f2i(v), 0x401f));   // lane ^ 16
  v2f s = xswap32_f(v);                                    // lane ^ 32
  return s.x + s.y;
}

__device__ __forceinline__ void amax2(float& v, int& i, float ov, int oi) {
  if (ov > v || (ov == v && oi < i)) { v = ov; i = oi; }
}

__device__ __forceinline__ void wave_argmax(float& v, int& idx) {
  amax2(v, idx, ROR_F(v, 0x121), ROR_I(idx, 0x121));
  amax2(v, idx, ROR_F(v, 0x122), ROR_I(idx, 0x122));
  amax2(v, idx, ROR_F(v, 0x124), ROR_I(idx, 0x124));
  amax2(v, idx, ROR_F(v, 0x128), ROR_I(idx, 0x128));
  amax2(v, idx, i2f(__builtin_amdgcn_ds_swizzle(f2i(v), 0x401f)),
        __builtin_amdgcn_ds_swizzle(idx, 0x401f));
#if __has_builtin(__builtin_amdgcn_permlane32_swap)
  {
    auto rv = __builtin_amdgcn_permlane32_swap((unsigned)f2i(v), (unsigned)f2i(v), false, false);
    auto ri = __builtin_amdgcn_permlane32_swap((unsigned)idx, (unsigned)idx, false, false);
    amax2(v, idx, i2f((int)rv[0]), (int)ri[0]);
    amax2(v, idx, i2f((int)rv[1]), (int)ri[1]);
  }
#else
  amax2(v, idx, __shfl_xor(v, 32, 64), __shfl_xor(idx, 32, 64));
#endif
}

// R14: maxpool einsum (10 p-weighted 100x100x100 GEMMs per block) moved to the
// matrix pipe via mfma_f32_16x16x32_f16 — it was ~60% of the VALU issue (10
// pk_fma per (c,k,r)). Outputs are bf16 (threshold 0.018) so f16 inputs with
// w^2 prescaled by 2^24 (avoids f16 subnormals; w^2 <= 1e-4) give ~0.004 err.
// Everything argmax-sensitive (plain cos dot, CROW, mean-att, epilogue) stays
// the R6-exact fp32 vector path. 512-thr blocks, __launch_bounds__(512,2)
// (cap 128, R6-proven no-spill regime; the 64-VGPR chase is abandoned — R13
// showed even split forms spill and issue MORE total work).
__global__ __launch_bounds__(512, 2) void match_kernel(
    const float* __restrict__ s1, const float* __restrict__ s2,
    const float* __restrict__ w1, const float* __restrict__ w2,
    const float* __restrict__ w3, const float* __restrict__ w4,
    const float* __restrict__ w5, const float* __restrict__ w6,
    const float* __restrict__ w7, const float* __restrict__ w8,
    float* __restrict__ out)
{
  const int dir  = blockIdx.x & 1;
  const int b    = blockIdx.x >> 1;
  const int doff = dir * DD;
  const int tid  = threadIdx.x;
  const int lane = tid & 63;
  const int wv   = tid >> 6;

  const float* wfull = dir ? w2 : w1;
  const float* wmax  = dir ? w4 : w3;
  const float* wmean = dir ? w6 : w5;
  const float* watt2 = dir ? w8 : w7;   // fwd: max-att (w7); bwd: mean-att (w8)

  // fp32 s2, d-chunked (R6 layout, argmax-exact paths).
  __shared__ __align__(16) float S2V[DC][TT + 1][4];          // 40.4 KB
  // f16 copies for the MFMA maxpool path. Rows padded to 112 (7 i/j-tiles of
  // 16), cols to 136 (K=128 pad + 8 so row stride 272B = 68 dw == 4 mod 32 ->
  // 2-way-free frag reads). Pad regions are zero.
  __shared__ __align__(16) _Float16 S1H[112][136];            // 30.5 KB
  __shared__ __align__(16) _Float16 S2H[112][136];            // 30.5 KB
  __shared__ __align__(16) _Float16 W2H[PP][136];             // 2.7 KB (w^2 * 2^24)
  __shared__ __align__(16) float W2SQ[PP][DD];                // 4 KB (fp32, norms)
  __shared__ float N2PI[TT];
  __shared__ float N2WI[TT][11];        // padded
  __shared__ float RMAXL[TT][11];       // maxpool pre-n1w results (f16-MFMA path)
  // Wave-private regions (wave owns rows [wv*NR, wv*NR+NR)).
  __shared__ __align__(16) float S1R[NR * NW][DD];
  __shared__ __align__(16) float CROW[NR * NW][DD];
  __shared__ float N1PI[NR * NW];
  __shared__ float N1WI[NR * NW][PP];
  __shared__ int   ARGJ[NR * NW];

  // ---- Phase 1a: s2 -> S2V fp32 + S2H f16 (zero-padded) ----
  for (int idx = tid; idx < 112 * 136; idx += 512) {
    int i = idx / 136, d = idx - i * 136;
    float v = 0.f;
    if (i < TT && d < DD) {
      v = s2[(i * BBATCH + b) * (2 * DD) + doff + d];
      S2V[d >> 2][i][d & 3] = v;
    }
    S2H[i][d] = (_Float16)v;
  }
  // ---- Phase 1b: s1 -> S1H f16 (zero-padded) ----
  for (int idx = tid; idx < 112 * 136; idx += 512) {
    int i = idx / 136, d = idx - i * 136;
    float v = 0.f;
    if (i < TT && d < DD) v = s1[(i * BBATCH + b) * (2 * DD) + doff + d];
    S1H[i][d] = (_Float16)v;
  }
  // ---- Phase 1c: w^2 in fp32 (norms) + f16 prescaled (MFMA A-prep) ----
  for (int idx = tid; idx < PP * 136; idx += 512) {
    int p = idx / 136, d = idx - p * 136;
    float v2 = 0.f;
    if (d < DD) {
      float w = wmax[p * DD + d];
      v2 = w * w;
      W2SQ[p][d] = v2;
    }
    W2H[p][d] = (_Float16)(v2 * WSCALE);
  }
  __syncthreads();

  // ---- Phase 2: s2 norms (fp32-exact, unchanged from R6) ----
  for (int task = tid; task < TT + TT * PP; task += 512) {
    if (task < TT) {
      int j = task;
      float a = 0.f;
      for (int c = 0; c < DC; ++c) {
        v4f f = *(const v4f*)&S2V[c][j][0];
#pragma unroll
        for (int k = 0; k < 4; ++k) a = fmaf(f[k], f[k], a);
      }
      N2PI[j] = 1.0f / sqrtf(fmaxf(a, FEPS));   // argmax-sensitive cos
    } else {
      int q = task - TT; int j = q / PP, p = q - j * PP;
      float a = 0.f;
      for (int c = 0; c < DC; ++c) {
        v4f f = *(const v4f*)&S2V[c][j][0];
        v4f w = *(const v4f*)&W2SQ[p][4 * c];
#pragma unroll
        for (int k = 0; k < 4; ++k) a = fmaf(f[k] * f[k], w[k], a);
      }
      N2WI[j][p] = rsqrtf(fmaxf(a, FEPS));
    }
  }
  __syncthreads();

  // ======== MFMA maxpool section: 70 tasks (p, i-tile) over 8 waves ========
  // Per task: A_p frags = S1H * W2H (f16 pk-mul), 7 j-tiles x 4 K-steps of
  // mfma_f32_16x16x32_f16; scale cols by N2WI, mask j>=100, running max over
  // j-tiles, then 4-step DPP ROR-max over the 16 cols -> RMAXL[i][p].
  // D-frag mapping (m89-verified): col = lane&15 (j), row = (lane>>4)*4+reg (i).
  // A/B frags: [idx = lane&15][k = (lane>>4)*8 + e] from row-major f16 LDS.
  {
    const int fi = lane & 15;
    const int ke = (lane >> 4) << 3;
    for (int t = wv; t < 70; t += NW) {
      int p  = t / 7;
      int it = t - p * 7;
      const int li = it * 16 + fi;
      f16x8 aw[4];
#pragma unroll
      for (int ks = 0; ks < 4; ++ks)
        aw[ks] = *(const f16x8*)&S1H[li][ks * 32 + ke] *
                 *(const f16x8*)&W2H[p][ks * 32 + ke];
      v4f rmax = {-3.4e38f, -3.4e38f, -3.4e38f, -3.4e38f};
      for (int jt = 0; jt < 7; ++jt) {
        const int lj = jt * 16 + fi;
        v4f acc = {0.f, 0.f, 0.f, 0.f};
#pragma unroll
        for (int ks = 0; ks < 4; ++ks)
          acc = __builtin_amdgcn_mfma_f32_16x16x32_f16(
              aw[ks], *(const f16x8*)&S2H[lj][ks * 32 + ke], acc, 0, 0, 0);
        const bool jok = lj < TT;
        const float sc = N2WI[jok ? lj : 0][p];
#pragma unroll
        for (int r = 0; r < 4; ++r) {
          float v = acc[r] * sc;
          rmax[r] = fmaxf(rmax[r], jok ? v : -3.4e38f);
        }
      }
#pragma unroll
      for (int r = 0; r < 4; ++r) {
        float m = rmax[r];
        m = fmaxf(m, ROR_F(m, 0x121));
        m = fmaxf(m, ROR_F(m, 0x122));
        m = fmaxf(m, ROR_F(m, 0x124));
        m = fmaxf(m, ROR_F(m, 0x128));
        rmax[r] = m;                       // col-max now in all 16 lanes of row
      }
      if (fi == 0) {
#pragma unroll
        for (int r = 0; r < 4; ++r) {
          int i = it * 16 + ((lane >> 4) << 2) + r;
          if (i < TT) RMAXL[i][p] = rmax[r];
        }
      }
    }
  }
  __syncthreads();
  // ---- After this point: ZERO barriers (R6-proven). LDS is read-only or
  // wave-private (S1R/CROW/N1*/ARGJ).

  const int  j0   = lane;
  const int  j1   = 64 + lane;
  const bool act1 = (j1 < TT);
  const int  j1c  = act1 ? j1 : (TT - 1);
  const bool actd = (64 + lane) < DD;
  const int  d1   = actd ? (64 + lane) : (DD - 1);
  const int  c0i  = lane >> 2, k0 = lane & 3;      // phase-D d0 = lane
  const int  c1i  = d1 >> 2,   k1 = d1 & 3;        // phase-D d1

  const int sl = wv * NR;

  // ---- 50 row-groups (2 rows) strided over 8 waves (R6 schedule) ----
  for (int g = wv; g < 50; g += NW) {
    const int i0 = g * NR;

    // wave-private S1R staging: 2 rows x 25 float4 chunks
    if (lane < NR * DC) {
      int rr = lane / DC, c = lane - rr * DC;
      *(v4f*)&S1R[sl + rr][4 * c] =
          *(const v4f*)&s1[((i0 + rr) * BBATCH + b) * (2 * DD) + doff + 4 * c];
    }

    // wave-private s1 norms (fp32-exact, unchanged)
    if (lane < NR * 11) {
      int rr = lane / 11, q = lane - rr * 11;
      if (q == 0) {
        float a = 0.f;
        for (int c = 0; c < DC; ++c) {
          v4f f = *(const v4f*)&S1R[sl + rr][4 * c];
#pragma unroll
          for (int k = 0; k < 4; ++k) a = fmaf(f[k], f[k], a);
        }
        N1PI[sl + rr] = 1.0f / sqrtf(fmaxf(a, FEPS));
      } else {
        int p = q - 1;
        float a = 0.f;
        for (int c = 0; c < DC; ++c) {
          v4f f = *(const v4f*)&S1R[sl + rr][4 * c];
          v4f w = *(const v4f*)&W2SQ[p][4 * c];
#pragma unroll
          for (int k = 0; k < 4; ++k) a = fmaf(f[k] * f[k], w[k], a);
        }
        N1WI[sl + rr][p] = rsqrtf(fmaxf(a, FEPS));
      }
    }

    float rs[NR] = {0, 0};
    v2f attp[NR] = {{0, 0}, {0, 0}};

    // ---- Phase B-lite: plain dot only (fp32, R6 mul+add order -> argmax-safe)
    float dot0[NR] = {0, 0};
    float dot1[NR] = {0, 0};
    for (int c = 0; c < DC; ++c) {
      v4f s2a4 = *(const v4f*)&S2V[c][j0][0];
      v4f s2b4 = *(const v4f*)&S2V[c][j1c][0];
      v4f s1v[NR];
#pragma unroll
      for (int r = 0; r < NR; ++r) s1v[r] = *(const v4f*)&S1R[sl + r][4 * c];
#pragma unroll
      for (int k = 0; k < 4; ++k) {
#pragma unroll
        for (int r = 0; r < NR; ++r) {
          float ta0 = s1v[r][k] * s2a4[k];
          float ta1 = s1v[r][k] * s2b4[k];
          dot0[r] += ta0;
          dot1[r] += ta1;
        }
      }
    }

    // ---- Phase C-lite: cos rows, rowsum, argmax; maxpool out from RMAXL ----
#pragma unroll
    for (int r = 0; r < NR; ++r) {
      float n1pi_r = N1PI[sl + r];
      float c0 = dot0[r] * (n1pi_r * N2PI[j0]);
      float c1 = dot1[r] * (n1pi_r * N2PI[j1c]);
      CROW[sl + r][j0] = c0;
      if (act1) CROW[sl + r][j1] = c1;
      rs[r] = wave_sum(c0 + (act1 ? c1 : 0.f));

      float mv = c0; int mi = j0;
      if (act1 && (c1 > mv)) { mv = c1; mi = j1; }
      wave_argmax(mv, mi);
      if (lane == 0) ARGJ[sl + r] = mi;

      if (lane < PP) {
        out[((i0 + r) * BBATCH + b) * OC + 20 + dir * PP + lane] =
            RMAXL[i0 + r][lane] * N1WI[sl + r][lane] * WSCALE_I;
      }
    }

    // ---- Phase D: mean-att accumulation (unchanged) ----
    for (int j = 0; j < TT; ++j) {
      v2f s2ab; s2ab.x = S2V[c0i][j][k0]; s2ab.y = S2V[c1i][j][k1];
#pragma unroll
      for (int r = 0; r < NR; ++r) {
        float cv = CROW[sl + r][j];
        v2f cc; cc.x = cv; cc.y = cv;
        attp[r] = __builtin_elementwise_fma(cc, s2ab, attp[r]);
      }
    }

#pragma unroll
    for (int r = 0; r < NR; ++r) {
      float inv = 1.0f / (rs[r] + FEPS);
      CROW[sl + r][lane] = attp[r].x * inv;
      if (actd) CROW[sl + r][64 + lane] = attp[r].y * inv;
    }

    // ---- Phase E: epilogue (unchanged): 60 tasks ----
    if (lane < NR * 30) {
      int tk = lane;
      int r = tk / 30;
      int q = tk - r * 30;
      int set = q / PP;
      int p = q - set * PP;
      const float* wrow = (set == 0 ? wfull : (set == 1 ? wmean : watt2)) + p * DD;
      // reference quirk: s2.reshape(-1,D)[argmax] == s2f[0, argmax, :] (fwd only)
      const float* gat = s2 + ARGJ[sl + r] * (2 * DD);
      float num = 0.f, nx = 0.f, ny = 0.f;
      for (int c = 0; c < DC; ++c) {
        v4f x4 = *(const v4f*)&S1R[sl + r][4 * c];
        v4f y4;
        if (set == 0)                     y4 = *(const v4f*)&S2V[c][TT - 1][0];
        else if (set == 1 || dir == 1)    y4 = *(const v4f*)&CROW[sl + r][4 * c];
        else                              y4 = *(const v4f*)&gat[4 * c];
        v4f w4 = *(const v4f*)&wrow[4 * c];
#pragma unroll
        for (int k = 0; k < 4; ++k) {
          float w2v = w4[k] * w4[k];
          num = fmaf(x4[k] * y4[k], w2v, num);
          nx  = fmaf(x4[k] * x4[k], w2v, nx);
          ny  = fmaf(y4[k] * y4[k], w2v, ny);
        }
      }
      float cres = num * rsqrtf(fmaxf(nx, FEPS)) * rsqrtf(fmaxf(ny, FEPS));
      int ch = (set == 0 ? 0 : (set == 1 ? 40 : 60)) + dir * PP + p;
      out[((i0 + r) * BBATCH + b) * OC + ch] = cres;
    }
  }
}

extern "C" void kernel_launch(void* const* d_in, const int* in_sizes, int n_in,
                              void* d_out, int out_size, void* d_ws, size_t ws_size,
                              hipStream_t stream) {
  const float* s1 = (const float*)d_in[0];
  const float* s2 = (const float*)d_in[1];
  match_kernel<<<dim3(512), dim3(512), 0, stream>>>(
      s1, s2,
      (const float*)d_in[2], (const float*)d_in[3],
      (const float*)d_in[4], (const float*)d_in[5],
      (const float*)d_in[6], (const float*)d_in[7],
      (const float*)d_in[8], (const float*)d_in[9],
      (float*)d_out);
}